// Round 2
// baseline (3433.804 us; speedup 1.0000x reference)
//
#include <hip/hip_runtime.h>
#include <math.h>

#define Bv 256
#define Sv 128
#define Cv 256
#define Tv 64
#define Dv 300
#define Hv 150
#define G4v 600   // 4*H

// ------------------------------------------------------------------
// row L2 norm (length 300), one wave per row: out[r] = max(||x_r||, 1e-8)
// ------------------------------------------------------------------
__global__ __launch_bounds__(256)
void row_norm_k(const float* __restrict__ x, int rows, float* __restrict__ out)
{
    int gtid = blockIdx.x * 256 + threadIdx.x;
    int wave = gtid >> 6;
    int lane = threadIdx.x & 63;
    if (wave >= rows) return;
    const float* row = x + (size_t)wave * Dv;
    float s = 0.f;
    for (int k = lane; k < Dv; k += 64) { float v = row[k]; s += v * v; }
    #pragma unroll
    for (int off = 32; off > 0; off >>= 1) s += __shfl_down(s, off, 64);
    if (lane == 0) out[wave] = fmaxf(sqrtf(s), 1e-8f);
}

// ------------------------------------------------------------------
// G[dir][s][b][0:600] = src_emb[b][s][:] @ Wx_dir + b_dir
// tiled fp32 GEMM: M=32768 (r=b*128+s), N=600 (pad to 640), K=300
// block: 256 thr, tile 128x128x16, 8x8 per thread
// ------------------------------------------------------------------
__global__ __launch_bounds__(256)
void gemm_xw_k(const float* __restrict__ A,
               const float* __restrict__ Wf, const float* __restrict__ bf,
               const float* __restrict__ Wb, const float* __restrict__ bb,
               float* __restrict__ Gout)
{
    const int mt  = blockIdx.x;   // 0..255
    const int nt  = blockIdx.y;   // 0..4
    const int dir = blockIdx.z;   // 0..1
    const float* W    = dir ? Wb : Wf;
    const float* bias = dir ? bb : bf;
    const int r0 = mt * 128;
    const int n0 = nt * 128;
    const int tid = threadIdx.x;

    __shared__ float As[16][132];
    __shared__ float Bs[16][132];

    float acc[8][8];
    #pragma unroll
    for (int i = 0; i < 8; ++i)
        #pragma unroll
        for (int j = 0; j < 8; ++j) acc[i][j] = 0.f;

    const int ka = tid & 15, ma = tid >> 4;     // A-slab loader coords
    const int nb = tid & 127, kb = tid >> 7;    // B-slab loader coords

    for (int k0 = 0; k0 < Dv; k0 += 16) {
        #pragma unroll
        for (int p = 0; p < 8; ++p) {
            int m  = ma + p * 16;
            int kk = k0 + ka;
            As[ka][m] = (kk < Dv) ? A[(size_t)(r0 + m) * Dv + kk] : 0.f;
        }
        #pragma unroll
        for (int p = 0; p < 8; ++p) {
            int k  = kb + p * 2;
            int kk = k0 + k;
            int nn = n0 + nb;
            Bs[k][nb] = (kk < Dv && nn < G4v) ? W[(size_t)kk * G4v + nn] : 0.f;
        }
        __syncthreads();
        const int ty = tid >> 4, tx = tid & 15;
        #pragma unroll
        for (int k = 0; k < 16; ++k) {
            float a[8], bv[8];
            *(float4*)&a[0]  = *(const float4*)&As[k][ty*8];
            *(float4*)&a[4]  = *(const float4*)&As[k][ty*8+4];
            *(float4*)&bv[0] = *(const float4*)&Bs[k][tx*8];
            *(float4*)&bv[4] = *(const float4*)&Bs[k][tx*8+4];
            #pragma unroll
            for (int i = 0; i < 8; ++i)
                #pragma unroll
                for (int j = 0; j < 8; ++j)
                    acc[i][j] = fmaf(a[i], bv[j], acc[i][j]);
        }
        __syncthreads();
    }

    const int ty = tid >> 4, tx = tid & 15;
    #pragma unroll
    for (int i = 0; i < 8; ++i) {
        int r    = r0 + ty*8 + i;
        int bidx = r >> 7;      // S = 128
        int s    = r & 127;
        float* orow = Gout + ((size_t)dir * Sv * Bv + (size_t)s * Bv + bidx) * G4v;
        #pragma unroll
        for (int j4 = 0; j4 < 8; j4 += 4) {
            int n = n0 + tx*8 + j4;
            if (n < G4v) {
                float4 v;
                v.x = acc[i][j4+0] + bias[n+0];
                v.y = acc[i][j4+1] + bias[n+1];
                v.z = acc[i][j4+2] + bias[n+2];
                v.w = acc[i][j4+3] + bias[n+3];
                *(float4*)&orow[n] = v;
            }
        }
    }
}

// ------------------------------------------------------------------
// LSTM recurrence. One block per (batch, dir). 640 threads (600 active),
// thread j holds column Wh[:,j] REGISTER-RESIDENT (150 VGPR, forced via
// fully-unrolled constant-index FMAs); h broadcast via LDS (same-address
// -> conflict-free). G row for step s+1 prefetched during step s's FMAs
// (accumulate into 0, add gcur at the end so the load has a full step
// to land). 4 partial sums break the 150-deep dependent FMA chain.
// ------------------------------------------------------------------
__device__ __forceinline__ float sigm(float x) { return 1.0f / (1.0f + expf(-x)); }

__global__ __launch_bounds__(640, 1)
void lstm_k(const float* __restrict__ G,      // [2][S][B][600], bias included
            const float* __restrict__ Wh_f, const float* __restrict__ Wh_b,
            float* __restrict__ out_src,      // [B][S][300]
            float* __restrict__ out_cell)     // [B][300]
{
    const int bid = blockIdx.x;     // 0..511
    const int b   = bid >> 1;
    const int dir = bid & 1;
    const float* Wh = dir ? Wh_b : Wh_f;
    const float* Gd = G + (size_t)dir * Sv * Bv * G4v;

    __shared__ float h_sh[Hv + 2];
    __shared__ float g_sh[G4v];

    const int t = threadIdx.x;
    const bool active = (t < G4v);

    float wh[Hv];
    if (active) {
        #pragma unroll
        for (int k = 0; k < Hv; ++k) wh[k] = Wh[(size_t)k * G4v + t];
    }
    if (t < Hv) h_sh[t] = 0.f;
    float c = 0.f;

    // prefetch G row for step 0
    const int ss0 = dir ? (Sv - 1) : 0;
    float gcur = active ? Gd[((size_t)ss0 * Bv + b) * G4v + t] : 0.f;
    __syncthreads();

    for (int s = 0; s < Sv; ++s) {
        const int ss  = dir ? (Sv - 1 - s) : s;
        const int ssn = dir ? (ss - 1) : (ss + 1);

        // prefetch next step's G row (dead on last iter)
        float gnext = 0.f;
        if (active && (s + 1 < Sv))
            gnext = Gd[((size_t)ssn * Bv + b) * G4v + t];

        if (active) {
            float a0 = 0.f, a1 = 0.f, a2 = 0.f, a3 = 0.f;
            #pragma unroll
            for (int k = 0; k < 148; k += 4) {
                a0 = fmaf(h_sh[k+0], wh[k+0], a0);
                a1 = fmaf(h_sh[k+1], wh[k+1], a1);
                a2 = fmaf(h_sh[k+2], wh[k+2], a2);
                a3 = fmaf(h_sh[k+3], wh[k+3], a3);
            }
            a0 = fmaf(h_sh[148], wh[148], a0);
            a1 = fmaf(h_sh[149], wh[149], a1);
            g_sh[t] = gcur + ((a0 + a1) + (a2 + a3));
        }
        __syncthreads();

        if (t < Hv) {
            float ig = sigm(g_sh[t]);
            float fg = sigm(g_sh[t + Hv]);
            float gg = tanhf(g_sh[t + 2*Hv]);
            float og = sigm(g_sh[t + 3*Hv]);
            c = fg * c + ig * gg;
            float h = og * tanhf(c);
            h_sh[t] = h;
            out_src[((size_t)b * Sv + ss) * (2*Hv) + dir*Hv + t] = h;
        }
        gcur = gnext;
        __syncthreads();
    }
    if (t < Hv) out_cell[(size_t)b * (2*Hv) + dir*Hv + t] = c;
}

// ------------------------------------------------------------------
// out[b][r][n] = emb + bias[n] + sum_q hot[b][r][q] * W[q][n]
// 64 rows per block
// ------------------------------------------------------------------
__global__ __launch_bounds__(256)
void init_enc_k(const float* __restrict__ emb, const float* __restrict__ hot,
                const float* __restrict__ W, const float* __restrict__ bias,
                int hd, float* __restrict__ outp)
{
    __shared__ float Wsh[9*300];
    __shared__ float bsh[300];
    __shared__ float hotsh[64*9];
    const int tid = threadIdx.x;
    const size_t r0 = (size_t)blockIdx.x * 64;
    for (int idx = tid; idx < hd*300; idx += 256) Wsh[idx] = W[idx];
    for (int idx = tid; idx < 300;    idx += 256) bsh[idx] = bias[idx];
    for (int idx = tid; idx < 64*hd;  idx += 256) hotsh[idx] = hot[r0*hd + idx];
    __syncthreads();
    for (int idx = tid; idx < 64*300; idx += 256) {
        int r = idx / 300;
        int n = idx - r*300;
        float v = emb[r0*300 + idx] + bsh[n];
        for (int q = 0; q < hd; ++q) v = fmaf(hotsh[r*hd+q], Wsh[q*300+n], v);
        outp[r0*300 + idx] = v;
    }
}

// ------------------------------------------------------------------
// sim[b][c][s] = dot(cmp[b,c,:], src[b,s,:]) / (cn[b,c]*sn[b,s])
// per-batch GEMM: M x 128, K=300.  block tile 64x128x16, 4x8/thread
// ------------------------------------------------------------------
__global__ __launch_bounds__(256)
void gemm_sim_k(const float* __restrict__ cmp, const float* __restrict__ src,
                const float* __restrict__ cn, const float* __restrict__ sn,
                int M, float* __restrict__ sim)
{
    const int b  = blockIdx.z;
    const int m0 = blockIdx.x * 64;
    const int tid = threadIdx.x;

    const float* A  = cmp + (size_t)b * M * Dv;    // [M,300]
    const float* Bm = src + (size_t)b * Sv * Dv;   // [128,300] (used transposed)

    __shared__ float As[16][68];
    __shared__ float Bs[16][132];

    float acc[4][8];
    #pragma unroll
    for (int i = 0; i < 4; ++i)
        #pragma unroll
        for (int j = 0; j < 8; ++j) acc[i][j] = 0.f;

    const int ka = tid & 15, mb = tid >> 4;

    for (int k0 = 0; k0 < Dv; k0 += 16) {
        int kk = k0 + ka;
        #pragma unroll
        for (int p = 0; p < 4; ++p) {
            int m = mb + p*16;
            As[ka][m] = (kk < Dv) ? A[(size_t)(m0 + m) * Dv + kk] : 0.f;
        }
        #pragma unroll
        for (int p = 0; p < 8; ++p) {
            int n = mb + p*16;   // s index
            Bs[ka][n] = (kk < Dv) ? Bm[(size_t)n * Dv + kk] : 0.f;
        }
        __syncthreads();
        const int ty = tid >> 4, tx = tid & 15;
        #pragma unroll
        for (int k = 0; k < 16; ++k) {
            float a[4], bv[8];
            *(float4*)&a[0]  = *(const float4*)&As[k][ty*4];
            *(float4*)&bv[0] = *(const float4*)&Bs[k][tx*8];
            *(float4*)&bv[4] = *(const float4*)&Bs[k][tx*8+4];
            #pragma unroll
            for (int i = 0; i < 4; ++i)
                #pragma unroll
                for (int j = 0; j < 8; ++j)
                    acc[i][j] = fmaf(a[i], bv[j], acc[i][j]);
        }
        __syncthreads();
    }

    const int ty = tid >> 4, tx = tid & 15;
    float cnv[4], snv[8];
    #pragma unroll
    for (int i = 0; i < 4; ++i) cnv[i] = cn[(size_t)b * M + m0 + ty*4 + i];
    #pragma unroll
    for (int j = 0; j < 8; ++j) snv[j] = sn[(size_t)b * Sv + tx*8 + j];
    #pragma unroll
    for (int i = 0; i < 4; ++i) {
        float* orow = sim + ((size_t)b * M + m0 + ty*4 + i) * Sv;
        #pragma unroll
        for (int j4 = 0; j4 < 8; j4 += 4) {
            float4 v;
            v.x = acc[i][j4+0] / (cnv[i] * snv[j4+0]);
            v.y = acc[i][j4+1] / (cnv[i] * snv[j4+1]);
            v.z = acc[i][j4+2] / (cnv[i] * snv[j4+2]);
            v.w = acc[i][j4+3] / (cnv[i] * snv[j4+3]);
            *(float4*)&orow[tx*8 + j4] = v;
        }
    }
}

// ------------------------------------------------------------------
// out[b][c][0:300] += sim[b][c][:] @ src_enc[b][:][0:300]
// per-batch GEMM: M x 300, K=128.  tile 64x64x16, 4x4/thread
// ------------------------------------------------------------------
__global__ __launch_bounds__(256)
void gemm_ctx_k(const float* __restrict__ sim, const float* __restrict__ enc,
                int M, float* __restrict__ outp)
{
    const int b  = blockIdx.z;
    const int m0 = blockIdx.x * 64;
    const int n0 = blockIdx.y * 64;
    const int tid = threadIdx.x;

    const float* A  = sim + (size_t)b * M * Sv;     // [M,128]
    const float* Bm = enc + (size_t)b * Sv * 300;   // [128,300]

    __shared__ float As[16][68];
    __shared__ float Bs[16][68];

    float acc[4][4];
    #pragma unroll
    for (int i = 0; i < 4; ++i)
        #pragma unroll
        for (int j = 0; j < 4; ++j) acc[i][j] = 0.f;

    const int ka  = tid & 15, mb2 = tid >> 4;
    const int nb3 = tid & 63, kb3 = tid >> 6;

    for (int k0 = 0; k0 < Sv; k0 += 16) {
        #pragma unroll
        for (int p = 0; p < 4; ++p) {
            int m = mb2 + p*16;
            As[ka][m] = A[(size_t)(m0 + m) * Sv + k0 + ka];
        }
        #pragma unroll
        for (int p = 0; p < 4; ++p) {
            int k  = kb3 + p*4;
            int nn = n0 + nb3;
            Bs[k][nb3] = (nn < 300) ? Bm[(size_t)(k0 + k) * 300 + nn] : 0.f;
        }
        __syncthreads();
        const int ty = tid >> 4, tx = tid & 15;
        #pragma unroll
        for (int k = 0; k < 16; ++k) {
            float a[4], bv[4];
            *(float4*)&a[0]  = *(const float4*)&As[k][ty*4];
            *(float4*)&bv[0] = *(const float4*)&Bs[k][tx*4];
            #pragma unroll
            for (int i = 0; i < 4; ++i)
                #pragma unroll
                for (int j = 0; j < 4; ++j)
                    acc[i][j] = fmaf(a[i], bv[j], acc[i][j]);
        }
        __syncthreads();
    }

    const int ty = tid >> 4, tx = tid & 15;
    int n = n0 + tx*4;
    if (n < 300) {
        #pragma unroll
        for (int i = 0; i < 4; ++i) {
            int row = m0 + ty*4 + i;
            float4* op = (float4*)(outp + ((size_t)b * M + row) * 300 + n);
            float4 v = *op;
            v.x += acc[i][0]; v.y += acc[i][1]; v.z += acc[i][2]; v.w += acc[i][3];
            *op = v;
        }
    }
}

// ------------------------------------------------------------------
extern "C" void kernel_launch(void* const* d_in, const int* in_sizes, int n_in,
                              void* d_out, int out_size, void* d_ws, size_t ws_size,
                              hipStream_t stream)
{
    (void)in_sizes; (void)n_in; (void)out_size; (void)ws_size;
    const float* src_emb = (const float*)d_in[0];
    const float* col_emb = (const float*)d_in[1];
    const float* tab_emb = (const float*)d_in[2];
    const float* col_hot = (const float*)d_in[3];
    const float* tab_hot = (const float*)d_in[4];
    const float* Wx_f = (const float*)d_in[5];
    const float* Wh_f = (const float*)d_in[6];
    const float* b_f  = (const float*)d_in[7];
    const float* Wx_b = (const float*)d_in[8];
    const float* Wh_b = (const float*)d_in[9];
    const float* b_b  = (const float*)d_in[10];
    const float* W_col = (const float*)d_in[11];
    const float* b_col = (const float*)d_in[12];
    const float* W_tab = (const float*)d_in[13];
    const float* b_tab = (const float*)d_in[14];

    float* out      = (float*)d_out;
    float* out_src  = out;                       // [256][128][300]
    float* out_col  = out + 9830400;             // [256][256][300]
    float* out_tab  = out + 29491200;            // [256][64][300]
    float* out_cell = out + 34406400;            // [256][300]

    float* ws = (float*)d_ws;
    float* Gbuf    = ws;                         // 2*128*256*600 = 39,321,600 floats
    float* sim_col = ws;                         // reused AFTER lstm: 8,388,608 floats
    float* sim_tab = ws + 8388608;               // 2,097,152 floats
    float* sn = ws + 39321600;                   // [B*S]  32768
    float* cn = sn + 32768;                      // [B*C]  65536
    float* tn = cn + 65536;                      // [B*T]  16384

    // 1. norms
    row_norm_k<<<32768/4, 256, 0, stream>>>(src_emb, 32768, sn);
    row_norm_k<<<65536/4, 256, 0, stream>>>(col_emb, 65536, cn);
    row_norm_k<<<16384/4, 256, 0, stream>>>(tab_emb, 16384, tn);

    // 2. input projection x@Wx + b for both directions
    gemm_xw_k<<<dim3(256, 5, 2), 256, 0, stream>>>(src_emb, Wx_f, b_f, Wx_b, b_b, Gbuf);

    // 3. recurrence
    lstm_k<<<512, 640, 0, stream>>>(Gbuf, Wh_f, Wh_b, out_src, out_cell);

    // 4. out = emb + hot@W + bias
    init_enc_k<<<65536/64, 256, 0, stream>>>(col_emb, col_hot, W_col, b_col, 9, out_col);
    init_enc_k<<<16384/64, 256, 0, stream>>>(tab_emb, tab_hot, W_tab, b_tab, 5, out_tab);

    // 5. cosine similarity (overwrites Gbuf region — must come after lstm_k)
    gemm_sim_k<<<dim3(4, 1, 256), 256, 0, stream>>>(col_emb, src_emb, cn, sn, 256, sim_col);
    gemm_sim_k<<<dim3(1, 1, 256), 256, 0, stream>>>(tab_emb, src_emb, tn, sn, 64, sim_tab);

    // 6. context accumulation
    gemm_ctx_k<<<dim3(4, 5, 256), 256, 0, stream>>>(sim_col, out_src, 256, out_col);
    gemm_ctx_k<<<dim3(1, 5, 256), 256, 0, stream>>>(sim_tab, out_src, 64, out_tab);
}

// Round 3
// 1137.606 us; speedup vs baseline: 3.0184x; 3.0184x over previous
//
#include <hip/hip_runtime.h>
#include <math.h>

#define Bv 256
#define Sv 128
#define Cv 256
#define Tv 64
#define Dv 300
#define Hv 150
#define G4v 600   // 4*H

typedef _Float16 h8v __attribute__((ext_vector_type(8)));
typedef float    f4v __attribute__((ext_vector_type(4)));

// ------------------------------------------------------------------
// row L2 norm (length 300), one wave per row: out[r] = max(||x_r||, 1e-8)
// ------------------------------------------------------------------
__global__ __launch_bounds__(256)
void row_norm_k(const float* __restrict__ x, int rows, float* __restrict__ out)
{
    int gtid = blockIdx.x * 256 + threadIdx.x;
    int wave = gtid >> 6;
    int lane = threadIdx.x & 63;
    if (wave >= rows) return;
    const float* row = x + (size_t)wave * Dv;
    float s = 0.f;
    for (int k = lane; k < Dv; k += 64) { float v = row[k]; s += v * v; }
    #pragma unroll
    for (int off = 32; off > 0; off >>= 1) s += __shfl_down(s, off, 64);
    if (lane == 0) out[wave] = fmaxf(sqrtf(s), 1e-8f);
}

// ------------------------------------------------------------------
// G[dir][s][b][0:600] = src_emb[b][s][:] @ Wx_dir + b_dir
// tiled fp32 GEMM: M=32768 (r=b*128+s), N=600, K=300
// ------------------------------------------------------------------
__global__ __launch_bounds__(256)
void gemm_xw_k(const float* __restrict__ A,
               const float* __restrict__ Wf, const float* __restrict__ bf,
               const float* __restrict__ Wb, const float* __restrict__ bb,
               float* __restrict__ Gout)
{
    const int mt  = blockIdx.x;   // 0..255
    const int nt  = blockIdx.y;   // 0..4
    const int dir = blockIdx.z;   // 0..1
    const float* W    = dir ? Wb : Wf;
    const float* bias = dir ? bb : bf;
    const int r0 = mt * 128;
    const int n0 = nt * 128;
    const int tid = threadIdx.x;

    __shared__ float As[16][132];
    __shared__ float Bs[16][132];

    float acc[8][8];
    #pragma unroll
    for (int i = 0; i < 8; ++i)
        #pragma unroll
        for (int j = 0; j < 8; ++j) acc[i][j] = 0.f;

    const int ka = tid & 15, ma = tid >> 4;
    const int nb = tid & 127, kb = tid >> 7;

    for (int k0 = 0; k0 < Dv; k0 += 16) {
        #pragma unroll
        for (int p = 0; p < 8; ++p) {
            int m  = ma + p * 16;
            int kk = k0 + ka;
            As[ka][m] = (kk < Dv) ? A[(size_t)(r0 + m) * Dv + kk] : 0.f;
        }
        #pragma unroll
        for (int p = 0; p < 8; ++p) {
            int k  = kb + p * 2;
            int kk = k0 + k;
            int nn = n0 + nb;
            Bs[k][nb] = (kk < Dv && nn < G4v) ? W[(size_t)kk * G4v + nn] : 0.f;
        }
        __syncthreads();
        const int ty = tid >> 4, tx = tid & 15;
        #pragma unroll
        for (int k = 0; k < 16; ++k) {
            float a[8], bv[8];
            *(float4*)&a[0]  = *(const float4*)&As[k][ty*8];
            *(float4*)&a[4]  = *(const float4*)&As[k][ty*8+4];
            *(float4*)&bv[0] = *(const float4*)&Bs[k][tx*8];
            *(float4*)&bv[4] = *(const float4*)&Bs[k][tx*8+4];
            #pragma unroll
            for (int i = 0; i < 8; ++i)
                #pragma unroll
                for (int j = 0; j < 8; ++j)
                    acc[i][j] = fmaf(a[i], bv[j], acc[i][j]);
        }
        __syncthreads();
    }

    const int ty = tid >> 4, tx = tid & 15;
    #pragma unroll
    for (int i = 0; i < 8; ++i) {
        int r    = r0 + ty*8 + i;
        int bidx = r >> 7;
        int s    = r & 127;
        float* orow = Gout + ((size_t)dir * Sv * Bv + (size_t)s * Bv + bidx) * G4v;
        #pragma unroll
        for (int j4 = 0; j4 < 8; j4 += 4) {
            int n = n0 + tx*8 + j4;
            if (n < G4v) {
                float4 v;
                v.x = acc[i][j4+0] + bias[n+0];
                v.y = acc[i][j4+1] + bias[n+1];
                v.z = acc[i][j4+2] + bias[n+2];
                v.w = acc[i][j4+3] + bias[n+3];
                *(float4*)&orow[n] = v;
            }
        }
    }
}

// ------------------------------------------------------------------
// MFMA LSTM recurrence. 128 blocks = 64 batch-groups x 2 dirs.
// Block: 640 threads (10 waves), NB=4 batches, M=16 MFMA rows (0..3 valid).
// Wave w owns hcols [16w,16w+16) for ALL 4 gates: B-frags (Wh, fp16) in
// 80 VGPRs loaded once. h state: fp16 LDS [2][16][168] double buffer.
// Per step: 5 ds_read_b128 A-frags + 20 mfma_f32_16x16x32_f16 per wave,
// wave-private g_sh transpose (no barrier), full-lane gate math (fp32),
// 1 barrier/step. G rows prefetched one step ahead.
// ------------------------------------------------------------------
__device__ __forceinline__ float sigm(float x) { return 1.0f / (1.0f + expf(-x)); }

__global__ __launch_bounds__(640, 3)
void lstm_mfma_k(const float* __restrict__ G,      // [2][S][B][600] bias incl.
                 const float* __restrict__ Wh_f, const float* __restrict__ Wh_b,
                 float* __restrict__ out_src,      // [B][S][300]
                 float* __restrict__ out_cell)     // [B][300]
{
    const int blk = blockIdx.x;          // 0..127
    const int dir = blk & 1;
    const int b0  = (blk >> 1) * 4;
    const float* Wh = dir ? Wh_b : Wh_f;
    const float* Gd = G + (size_t)dir * Sv * Bv * G4v;

    const int tid  = threadIdx.x;
    const int w    = tid >> 6;           // wave 0..9
    const int lane = tid & 63;
    const int q    = lane >> 4;          // 0..3  (= k-chunk in A, = row in phase B)
    const int cp   = lane & 15;          // 0..15 (= M row in A, = col in phase B)
    const int hcol = w * 16 + cp;        // 0..159
    const bool colok = (hcol < Hv);

    __shared__ _Float16 h_sh[2][16][168];
    __shared__ float    g_sh[10][4][16][4];   // [wave][gate][col][row]

    // ---- one-time: load Wh B-fragments into registers (fp16) ----
    h8v Bf[4][5];
    #pragma unroll
    for (int g = 0; g < 4; ++g) {
        #pragma unroll
        for (int ks = 0; ks < 5; ++ks) {
            h8v v;
            #pragma unroll
            for (int j = 0; j < 8; ++j) {
                int k = 32*ks + 8*q + j;
                float x = (k < Hv && colok) ? Wh[(size_t)k * G4v + g*Hv + hcol] : 0.f;
                v[j] = (_Float16)x;
            }
            Bf[g][ks] = v;
        }
    }

    // zero h state (rows 4..15 stay zero forever)
    for (int i = tid; i < 2*16*168; i += 640)
        ((_Float16*)h_sh)[i] = (_Float16)0.f;

    float c = 0.f;
    const int rp = q;   // phase-B row (batch) this lane owns

    // prefetch G for step 0
    float gc0, gc1, gc2, gc3;
    {
        int ss0 = dir ? (Sv - 1) : 0;
        const float* p = Gd + ((size_t)ss0 * Bv + b0 + rp) * G4v;
        gc0 = colok ? p[0*Hv + hcol] : 0.f;
        gc1 = colok ? p[1*Hv + hcol] : 0.f;
        gc2 = colok ? p[2*Hv + hcol] : 0.f;
        gc3 = colok ? p[3*Hv + hcol] : 0.f;
    }
    __syncthreads();

    int cur = 0;
    for (int s = 0; s < Sv; ++s) {
        const int ss = dir ? (Sv - 1 - s) : s;

        // ---- MFMA phase: acc[g] = h @ Wh[:, gate g cols] ----
        f4v a0 = {0.f,0.f,0.f,0.f}, a1 = a0, a2 = a0, a3 = a0;
        #pragma unroll
        for (int ks = 0; ks < 5; ++ks) {
            h8v af = *(const h8v*)&h_sh[cur][cp][32*ks + 8*q];
            a0 = __builtin_amdgcn_mfma_f32_16x16x32_f16(af, Bf[0][ks], a0, 0, 0, 0);
            a1 = __builtin_amdgcn_mfma_f32_16x16x32_f16(af, Bf[1][ks], a1, 0, 0, 0);
            a2 = __builtin_amdgcn_mfma_f32_16x16x32_f16(af, Bf[2][ks], a2, 0, 0, 0);
            a3 = __builtin_amdgcn_mfma_f32_16x16x32_f16(af, Bf[3][ks], a3, 0, 0, 0);
        }

        // ---- prefetch next step's G (hidden under this step) ----
        float gn0 = 0.f, gn1 = 0.f, gn2 = 0.f, gn3 = 0.f;
        if (s + 1 < Sv) {
            int ssn = dir ? (ss - 1) : (ss + 1);
            const float* p = Gd + ((size_t)ssn * Bv + b0 + rp) * G4v;
            if (colok) {
                gn0 = p[0*Hv + hcol]; gn1 = p[1*Hv + hcol];
                gn2 = p[2*Hv + hcol]; gn3 = p[3*Hv + hcol];
            }
        }

        // ---- wave-private transpose: (row=reg, col=lane) -> (row=q, col=cp) ----
        if (q == 0) {
            *(f4v*)&g_sh[w][0][cp][0] = a0;
            *(f4v*)&g_sh[w][1][cp][0] = a1;
            *(f4v*)&g_sh[w][2][cp][0] = a2;
            *(f4v*)&g_sh[w][3][cp][0] = a3;
        }
        // same-wave LDS dep: compiler inserts lgkmcnt wait
        float gi = g_sh[w][0][cp][rp] + gc0;
        float gf = g_sh[w][1][cp][rp] + gc1;
        float gg = g_sh[w][2][cp][rp] + gc2;
        float go = g_sh[w][3][cp][rp] + gc3;

        float I  = sigm(gi);
        float F  = sigm(gf);
        float Gt = tanhf(gg);
        float O  = sigm(go);
        c = F * c + I * Gt;
        float h = O * tanhf(c);

        // h -> next A buffer (fp16); out_src (fp32)
        h_sh[cur ^ 1][rp][hcol] = (_Float16)h;
        if (colok)
            out_src[(((size_t)(b0 + rp)) * Sv + ss) * (2*Hv) + dir*Hv + hcol] = h;

        gc0 = gn0; gc1 = gn1; gc2 = gn2; gc3 = gn3;
        cur ^= 1;
        __syncthreads();
    }

    if (colok)
        out_cell[(size_t)(b0 + rp) * (2*Hv) + dir*Hv + hcol] = c;
}

// ------------------------------------------------------------------
// out[b][r][n] = emb + bias[n] + sum_q hot[b][r][q] * W[q][n]
// ------------------------------------------------------------------
__global__ __launch_bounds__(256)
void init_enc_k(const float* __restrict__ emb, const float* __restrict__ hot,
                const float* __restrict__ W, const float* __restrict__ bias,
                int hd, float* __restrict__ outp)
{
    __shared__ float Wsh[9*300];
    __shared__ float bsh[300];
    __shared__ float hotsh[64*9];
    const int tid = threadIdx.x;
    const size_t r0 = (size_t)blockIdx.x * 64;
    for (int idx = tid; idx < hd*300; idx += 256) Wsh[idx] = W[idx];
    for (int idx = tid; idx < 300;    idx += 256) bsh[idx] = bias[idx];
    for (int idx = tid; idx < 64*hd;  idx += 256) hotsh[idx] = hot[r0*hd + idx];
    __syncthreads();
    for (int idx = tid; idx < 64*300; idx += 256) {
        int r = idx / 300;
        int n = idx - r*300;
        float v = emb[r0*300 + idx] + bsh[n];
        for (int q = 0; q < hd; ++q) v = fmaf(hotsh[r*hd+q], Wsh[q*300+n], v);
        outp[r0*300 + idx] = v;
    }
}

// ------------------------------------------------------------------
// sim[b][c][s] = dot(cmp[b,c,:], src[b,s,:]) / (cn[b,c]*sn[b,s])
// ------------------------------------------------------------------
__global__ __launch_bounds__(256)
void gemm_sim_k(const float* __restrict__ cmp, const float* __restrict__ src,
                const float* __restrict__ cn, const float* __restrict__ sn,
                int M, float* __restrict__ sim)
{
    const int b  = blockIdx.z;
    const int m0 = blockIdx.x * 64;
    const int tid = threadIdx.x;

    const float* A  = cmp + (size_t)b * M * Dv;
    const float* Bm = src + (size_t)b * Sv * Dv;

    __shared__ float As[16][68];
    __shared__ float Bs[16][132];

    float acc[4][8];
    #pragma unroll
    for (int i = 0; i < 4; ++i)
        #pragma unroll
        for (int j = 0; j < 8; ++j) acc[i][j] = 0.f;

    const int ka = tid & 15, mb = tid >> 4;

    for (int k0 = 0; k0 < Dv; k0 += 16) {
        int kk = k0 + ka;
        #pragma unroll
        for (int p = 0; p < 4; ++p) {
            int m = mb + p*16;
            As[ka][m] = (kk < Dv) ? A[(size_t)(m0 + m) * Dv + kk] : 0.f;
        }
        #pragma unroll
        for (int p = 0; p < 8; ++p) {
            int n = mb + p*16;
            Bs[ka][n] = (kk < Dv) ? Bm[(size_t)n * Dv + kk] : 0.f;
        }
        __syncthreads();
        const int ty = tid >> 4, tx = tid & 15;
        #pragma unroll
        for (int k = 0; k < 16; ++k) {
            float a[4], bv[8];
            *(float4*)&a[0]  = *(const float4*)&As[k][ty*4];
            *(float4*)&bv[0] = *(const float4*)&Bs[k][tx*8];
            *(float4*)&bv[4] = *(const float4*)&Bs[k][tx*8+4];
            #pragma unroll
            for (int i = 0; i < 4; ++i)
                #pragma unroll
                for (int j = 0; j < 8; ++j)
                    acc[i][j] = fmaf(a[i], bv[j], acc[i][j]);
        }
        __syncthreads();
    }

    const int ty = tid >> 4, tx = tid & 15;
    float cnv[4], snv[8];
    #pragma unroll
    for (int i = 0; i < 4; ++i) cnv[i] = cn[(size_t)b * M + m0 + ty*4 + i];
    #pragma unroll
    for (int j = 0; j < 8; ++j) snv[j] = sn[(size_t)b * Sv + tx*8 + j];
    #pragma unroll
    for (int i = 0; i < 4; ++i) {
        float* orow = sim + ((size_t)b * M + m0 + ty*4 + i) * Sv;
        #pragma unroll
        for (int j4 = 0; j4 < 8; j4 += 4) {
            float4 v;
            v.x = acc[i][j4+0] / (cnv[i] * snv[j4+0]);
            v.y = acc[i][j4+1] / (cnv[i] * snv[j4+1]);
            v.z = acc[i][j4+2] / (cnv[i] * snv[j4+2]);
            v.w = acc[i][j4+3] / (cnv[i] * snv[j4+3]);
            *(float4*)&orow[tx*8 + j4] = v;
        }
    }
}

// ------------------------------------------------------------------
// out[b][c][0:300] += sim[b][c][:] @ src_enc[b][:][0:300]
// ------------------------------------------------------------------
__global__ __launch_bounds__(256)
void gemm_ctx_k(const float* __restrict__ sim, const float* __restrict__ enc,
                int M, float* __restrict__ outp)
{
    const int b  = blockIdx.z;
    const int m0 = blockIdx.x * 64;
    const int n0 = blockIdx.y * 64;
    const int tid = threadIdx.x;

    const float* A  = sim + (size_t)b * M * Sv;
    const float* Bm = enc + (size_t)b * Sv * 300;

    __shared__ float As[16][68];
    __shared__ float Bs[16][68];

    float acc[4][4];
    #pragma unroll
    for (int i = 0; i < 4; ++i)
        #pragma unroll
        for (int j = 0; j < 4; ++j) acc[i][j] = 0.f;

    const int ka  = tid & 15, mb2 = tid >> 4;
    const int nb3 = tid & 63, kb3 = tid >> 6;

    for (int k0 = 0; k0 < Sv; k0 += 16) {
        #pragma unroll
        for (int p = 0; p < 4; ++p) {
            int m = mb2 + p*16;
            As[ka][m] = A[(size_t)(m0 + m) * Sv + k0 + ka];
        }
        #pragma unroll
        for (int p = 0; p < 4; ++p) {
            int k  = kb3 + p*4;
            int nn = n0 + nb3;
            Bs[k][nb3] = (nn < 300) ? Bm[(size_t)(k0 + k) * 300 + nn] : 0.f;
        }
        __syncthreads();
        const int ty = tid >> 4, tx = tid & 15;
        #pragma unroll
        for (int k = 0; k < 16; ++k) {
            float a[4], bv[4];
            *(float4*)&a[0]  = *(const float4*)&As[k][ty*4];
            *(float4*)&bv[0] = *(const float4*)&Bs[k][tx*4];
            #pragma unroll
            for (int i = 0; i < 4; ++i)
                #pragma unroll
                for (int j = 0; j < 4; ++j)
                    acc[i][j] = fmaf(a[i], bv[j], acc[i][j]);
        }
        __syncthreads();
    }

    const int ty = tid >> 4, tx = tid & 15;
    int n = n0 + tx*4;
    if (n < 300) {
        #pragma unroll
        for (int i = 0; i < 4; ++i) {
            int row = m0 + ty*4 + i;
            float4* op = (float4*)(outp + ((size_t)b * M + row) * 300 + n);
            float4 v = *op;
            v.x += acc[i][0]; v.y += acc[i][1]; v.z += acc[i][2]; v.w += acc[i][3];
            *op = v;
        }
    }
}

// ------------------------------------------------------------------
extern "C" void kernel_launch(void* const* d_in, const int* in_sizes, int n_in,
                              void* d_out, int out_size, void* d_ws, size_t ws_size,
                              hipStream_t stream)
{
    (void)in_sizes; (void)n_in; (void)out_size; (void)ws_size;
    const float* src_emb = (const float*)d_in[0];
    const float* col_emb = (const float*)d_in[1];
    const float* tab_emb = (const float*)d_in[2];
    const float* col_hot = (const float*)d_in[3];
    const float* tab_hot = (const float*)d_in[4];
    const float* Wx_f = (const float*)d_in[5];
    const float* Wh_f = (const float*)d_in[6];
    const float* b_f  = (const float*)d_in[7];
    const float* Wx_b = (const float*)d_in[8];
    const float* Wh_b = (const float*)d_in[9];
    const float* b_b  = (const float*)d_in[10];
    const float* W_col = (const float*)d_in[11];
    const float* b_col = (const float*)d_in[12];
    const float* W_tab = (const float*)d_in[13];
    const float* b_tab = (const float*)d_in[14];

    float* out      = (float*)d_out;
    float* out_src  = out;                       // [256][128][300]
    float* out_col  = out + 9830400;             // [256][256][300]
    float* out_tab  = out + 29491200;            // [256][64][300]
    float* out_cell = out + 34406400;            // [256][300]

    float* ws = (float*)d_ws;
    float* Gbuf    = ws;                         // 2*128*256*600 floats
    float* sim_col = ws;                         // reused AFTER lstm
    float* sim_tab = ws + 8388608;
    float* sn = ws + 39321600;
    float* cn = sn + 32768;
    float* tn = cn + 65536;

    // 1. norms
    row_norm_k<<<32768/4, 256, 0, stream>>>(src_emb, 32768, sn);
    row_norm_k<<<65536/4, 256, 0, stream>>>(col_emb, 65536, cn);
    row_norm_k<<<16384/4, 256, 0, stream>>>(tab_emb, 16384, tn);

    // 2. input projection x@Wx + b for both directions
    gemm_xw_k<<<dim3(256, 5, 2), 256, 0, stream>>>(src_emb, Wx_f, b_f, Wx_b, b_b, Gbuf);

    // 3. recurrence (MFMA)
    lstm_mfma_k<<<128, 640, 0, stream>>>(Gbuf, Wh_f, Wh_b, out_src, out_cell);

    // 4. out = emb + hot@W + bias
    init_enc_k<<<65536/64, 256, 0, stream>>>(col_emb, col_hot, W_col, b_col, 9, out_col);
    init_enc_k<<<16384/64, 256, 0, stream>>>(tab_emb, tab_hot, W_tab, b_tab, 5, out_tab);

    // 5. cosine similarity (overwrites Gbuf region — must come after lstm)
    gemm_sim_k<<<dim3(4, 1, 256), 256, 0, stream>>>(col_emb, src_emb, cn, sn, 256, sim_col);
    gemm_sim_k<<<dim3(1, 1, 256), 256, 0, stream>>>(tab_emb, src_emb, tn, sn, 64, sim_tab);

    // 6. context accumulation
    gemm_ctx_k<<<dim3(4, 5, 256), 256, 0, stream>>>(sim_col, out_src, 256, out_col);
    gemm_ctx_k<<<dim3(1, 5, 256), 256, 0, stream>>>(sim_tab, out_src, 64, out_tab);
}

// Round 4
// 768.310 us; speedup vs baseline: 4.4693x; 1.4807x over previous
//
#include <hip/hip_runtime.h>
#include <math.h>

#define Bv 256
#define Sv 128
#define Cv 256
#define Tv 64
#define Dv 300
#define Hv 150
#define G4v 600   // 4*H

typedef _Float16 h8v __attribute__((ext_vector_type(8)));
typedef _Float16 h4v __attribute__((ext_vector_type(4)));
typedef float    f4v __attribute__((ext_vector_type(4)));

// ------------------------------------------------------------------
// row L2 norm (length 300), one wave per row: out[r] = max(||x_r||, 1e-8)
// ------------------------------------------------------------------
__global__ __launch_bounds__(256)
void row_norm_k(const float* __restrict__ x, int rows, float* __restrict__ out)
{
    int gtid = blockIdx.x * 256 + threadIdx.x;
    int wave = gtid >> 6;
    int lane = threadIdx.x & 63;
    if (wave >= rows) return;
    const float* row = x + (size_t)wave * Dv;
    float s = 0.f;
    for (int k = lane; k < Dv; k += 64) { float v = row[k]; s += v * v; }
    #pragma unroll
    for (int off = 32; off > 0; off >>= 1) s += __shfl_down(s, off, 64);
    if (lane == 0) out[wave] = fmaxf(sqrtf(s), 1e-8f);
}

// ------------------------------------------------------------------
// src_emb fp32 [32768][300] -> A16 fp16 [32768][320] (k>=300 zero)
// ------------------------------------------------------------------
__global__ __launch_bounds__(256)
void conv_a16_k(const float* __restrict__ A, _Float16* __restrict__ A16)
{
    int idx = blockIdx.x * 256 + threadIdx.x;   // 0 .. 32768*80-1
    int row = idx / 80;
    int k   = (idx - row * 80) * 4;
    float4 v = {0.f, 0.f, 0.f, 0.f};
    if (k < Dv) v = *(const float4*)&A[(size_t)row * Dv + k];
    h4v o;
    o[0] = (_Float16)v.x; o[1] = (_Float16)v.y;
    o[2] = (_Float16)v.z; o[3] = (_Float16)v.w;
    *(h4v*)&A16[(size_t)row * 320 + k] = o;
}

// ------------------------------------------------------------------
// Wx fp32 [300][600] -> W16T fp16 [dir][640][320] transposed, zero-padded
// ------------------------------------------------------------------
__global__ __launch_bounds__(320)
void conv_w16_k(const float* __restrict__ Wf, const float* __restrict__ Wb,
                _Float16* __restrict__ W16T)
{
    const int n   = blockIdx.x;      // 0..639
    const int dir = blockIdx.y;      // 0..1
    const int k   = threadIdx.x;     // 0..319
    const float* W = dir ? Wb : Wf;
    float v = (k < Dv && n < G4v) ? W[(size_t)k * G4v + n] : 0.f;
    W16T[((size_t)dir * 640 + n) * 320 + k] = (_Float16)v;
}

// ------------------------------------------------------------------
// MFMA input projection: G[dir][s][b][0:600] = src @ Wx_dir + b_dir
// A16 [32768][320] fp16 (row r = b*128+s), W16T [dir][640][320] fp16.
// Block 256 thr (4 waves), tile 128x128x32; wave = 64x64 quadrant via
// 16x mfma_f32_16x16x32_f16. LDS [128][40]-padded (conflict-balanced).
// ------------------------------------------------------------------
__global__ __launch_bounds__(256)
void gemm_xw_mfma_k(const _Float16* __restrict__ A16,
                    const _Float16* __restrict__ W16T,
                    const float* __restrict__ bf, const float* __restrict__ bb,
                    float* __restrict__ Gout)
{
    const int m0  = blockIdx.x * 128;
    const int n0  = blockIdx.y * 128;
    const int dir = blockIdx.z;
    const float* bias = dir ? bb : bf;
    const _Float16* Wd = W16T + (size_t)dir * 640 * 320;

    __shared__ _Float16 As[128][40];
    __shared__ _Float16 Bs[128][40];

    const int tid  = threadIdx.x;
    const int lane = tid & 63;
    const int w    = tid >> 6;
    const int wm   = w >> 1, wn = w & 1;
    const int r16  = lane & 15, q = lane >> 4;

    const int srow  = tid >> 1;          // staging row 0..127
    const int sslot = (tid & 1) * 16;    // halfs 0 or 16

    f4v acc[4][4];
    #pragma unroll
    for (int i = 0; i < 4; ++i)
        #pragma unroll
        for (int j = 0; j < 4; ++j) acc[i][j] = (f4v){0.f,0.f,0.f,0.f};

    for (int k0 = 0; k0 < 320; k0 += 32) {
        // global loads first (no LDS touch) so latency overlaps the barrier
        h8v av0 = *(const h8v*)&A16[(size_t)(m0 + srow) * 320 + k0 + sslot];
        h8v av1 = *(const h8v*)&A16[(size_t)(m0 + srow) * 320 + k0 + sslot + 8];
        h8v bv0 = *(const h8v*)&Wd [(size_t)(n0 + srow) * 320 + k0 + sslot];
        h8v bv1 = *(const h8v*)&Wd [(size_t)(n0 + srow) * 320 + k0 + sslot + 8];
        __syncthreads();   // prior iteration's frag reads complete
        *(h8v*)&As[srow][sslot]     = av0;
        *(h8v*)&As[srow][sslot + 8] = av1;
        *(h8v*)&Bs[srow][sslot]     = bv0;
        *(h8v*)&Bs[srow][sslot + 8] = bv1;
        __syncthreads();   // tiles ready

        h8v af[4], bfr[4];
        #pragma unroll
        for (int mi = 0; mi < 4; ++mi)
            af[mi] = *(const h8v*)&As[wm*64 + mi*16 + r16][q*8];
        #pragma unroll
        for (int ni = 0; ni < 4; ++ni)
            bfr[ni] = *(const h8v*)&Bs[wn*64 + ni*16 + r16][q*8];
        #pragma unroll
        for (int mi = 0; mi < 4; ++mi)
            #pragma unroll
            for (int ni = 0; ni < 4; ++ni)
                acc[mi][ni] = __builtin_amdgcn_mfma_f32_16x16x32_f16(
                                  af[mi], bfr[ni], acc[mi][ni], 0, 0, 0);
    }

    // epilogue: C/D layout col=lane&15, row=4*(lane>>4)+reg  (m89-verified)
    #pragma unroll
    for (int ni = 0; ni < 4; ++ni) {
        int n = n0 + wn*64 + ni*16 + r16;
        if (n >= G4v) continue;
        float bn = bias[n];
        #pragma unroll
        for (int mi = 0; mi < 4; ++mi) {
            #pragma unroll
            for (int r = 0; r < 4; ++r) {
                int row = m0 + wm*64 + mi*16 + q*4 + r;
                int b   = row >> 7;        // r = b*128 + s
                int s   = row & 127;
                Gout[(((size_t)dir * Sv + s) * Bv + b) * G4v + n] = acc[mi][ni][r] + bn;
            }
        }
    }
}

// ------------------------------------------------------------------
// MFMA LSTM recurrence (unchanged from round 3).
// ------------------------------------------------------------------
__device__ __forceinline__ float sigm(float x) { return 1.0f / (1.0f + expf(-x)); }

__global__ __launch_bounds__(640, 3)
void lstm_mfma_k(const float* __restrict__ G,      // [2][S][B][600] bias incl.
                 const float* __restrict__ Wh_f, const float* __restrict__ Wh_b,
                 float* __restrict__ out_src,      // [B][S][300]
                 float* __restrict__ out_cell)     // [B][300]
{
    const int blk = blockIdx.x;          // 0..127
    const int dir = blk & 1;
    const int b0  = (blk >> 1) * 4;
    const float* Wh = dir ? Wh_b : Wh_f;
    const float* Gd = G + (size_t)dir * Sv * Bv * G4v;

    const int tid  = threadIdx.x;
    const int w    = tid >> 6;           // wave 0..9
    const int lane = tid & 63;
    const int q    = lane >> 4;          // 0..3
    const int cp   = lane & 15;          // 0..15
    const int hcol = w * 16 + cp;        // 0..159
    const bool colok = (hcol < Hv);

    __shared__ _Float16 h_sh[2][16][168];
    __shared__ float    g_sh[10][4][16][4];   // [wave][gate][col][row]

    h8v Bf[4][5];
    #pragma unroll
    for (int g = 0; g < 4; ++g) {
        #pragma unroll
        for (int ks = 0; ks < 5; ++ks) {
            h8v v;
            #pragma unroll
            for (int j = 0; j < 8; ++j) {
                int k = 32*ks + 8*q + j;
                float x = (k < Hv && colok) ? Wh[(size_t)k * G4v + g*Hv + hcol] : 0.f;
                v[j] = (_Float16)x;
            }
            Bf[g][ks] = v;
        }
    }

    for (int i = tid; i < 2*16*168; i += 640)
        ((_Float16*)h_sh)[i] = (_Float16)0.f;

    float c = 0.f;
    const int rp = q;

    float gc0, gc1, gc2, gc3;
    {
        int ss0 = dir ? (Sv - 1) : 0;
        const float* p = Gd + ((size_t)ss0 * Bv + b0 + rp) * G4v;
        gc0 = colok ? p[0*Hv + hcol] : 0.f;
        gc1 = colok ? p[1*Hv + hcol] : 0.f;
        gc2 = colok ? p[2*Hv + hcol] : 0.f;
        gc3 = colok ? p[3*Hv + hcol] : 0.f;
    }
    __syncthreads();

    int cur = 0;
    for (int s = 0; s < Sv; ++s) {
        const int ss = dir ? (Sv - 1 - s) : s;

        f4v a0 = {0.f,0.f,0.f,0.f}, a1 = a0, a2 = a0, a3 = a0;
        #pragma unroll
        for (int ks = 0; ks < 5; ++ks) {
            h8v af = *(const h8v*)&h_sh[cur][cp][32*ks + 8*q];
            a0 = __builtin_amdgcn_mfma_f32_16x16x32_f16(af, Bf[0][ks], a0, 0, 0, 0);
            a1 = __builtin_amdgcn_mfma_f32_16x16x32_f16(af, Bf[1][ks], a1, 0, 0, 0);
            a2 = __builtin_amdgcn_mfma_f32_16x16x32_f16(af, Bf[2][ks], a2, 0, 0, 0);
            a3 = __builtin_amdgcn_mfma_f32_16x16x32_f16(af, Bf[3][ks], a3, 0, 0, 0);
        }

        float gn0 = 0.f, gn1 = 0.f, gn2 = 0.f, gn3 = 0.f;
        if (s + 1 < Sv) {
            int ssn = dir ? (ss - 1) : (ss + 1);
            const float* p = Gd + ((size_t)ssn * Bv + b0 + rp) * G4v;
            if (colok) {
                gn0 = p[0*Hv + hcol]; gn1 = p[1*Hv + hcol];
                gn2 = p[2*Hv + hcol]; gn3 = p[3*Hv + hcol];
            }
        }

        if (q == 0) {
            *(f4v*)&g_sh[w][0][cp][0] = a0;
            *(f4v*)&g_sh[w][1][cp][0] = a1;
            *(f4v*)&g_sh[w][2][cp][0] = a2;
            *(f4v*)&g_sh[w][3][cp][0] = a3;
        }
        float gi = g_sh[w][0][cp][rp] + gc0;
        float gf = g_sh[w][1][cp][rp] + gc1;
        float gg = g_sh[w][2][cp][rp] + gc2;
        float go = g_sh[w][3][cp][rp] + gc3;

        float I  = sigm(gi);
        float F  = sigm(gf);
        float Gt = tanhf(gg);
        float O  = sigm(go);
        c = F * c + I * Gt;
        float h = O * tanhf(c);

        h_sh[cur ^ 1][rp][hcol] = (_Float16)h;
        if (colok)
            out_src[(((size_t)(b0 + rp)) * Sv + ss) * (2*Hv) + dir*Hv + hcol] = h;

        gc0 = gn0; gc1 = gn1; gc2 = gn2; gc3 = gn3;
        cur ^= 1;
        __syncthreads();
    }

    if (colok)
        out_cell[(size_t)(b0 + rp) * (2*Hv) + dir*Hv + hcol] = c;
}

// ------------------------------------------------------------------
// out[b][r][n] = emb + bias[n] + sum_q hot[b][r][q] * W[q][n]
// ------------------------------------------------------------------
__global__ __launch_bounds__(256)
void init_enc_k(const float* __restrict__ emb, const float* __restrict__ hot,
                const float* __restrict__ W, const float* __restrict__ bias,
                int hd, float* __restrict__ outp)
{
    __shared__ float Wsh[9*300];
    __shared__ float bsh[300];
    __shared__ float hotsh[64*9];
    const int tid = threadIdx.x;
    const size_t r0 = (size_t)blockIdx.x * 64;
    for (int idx = tid; idx < hd*300; idx += 256) Wsh[idx] = W[idx];
    for (int idx = tid; idx < 300;    idx += 256) bsh[idx] = bias[idx];
    for (int idx = tid; idx < 64*hd;  idx += 256) hotsh[idx] = hot[r0*hd + idx];
    __syncthreads();
    for (int idx = tid; idx < 64*300; idx += 256) {
        int r = idx / 300;
        int n = idx - r*300;
        float v = emb[r0*300 + idx] + bsh[n];
        for (int q = 0; q < hd; ++q) v = fmaf(hotsh[r*hd+q], Wsh[q*300+n], v);
        outp[r0*300 + idx] = v;
    }
}

// ------------------------------------------------------------------
// sim[b][c][s] = dot(cmp[b,c,:], src[b,s,:]) / (cn[b,c]*sn[b,s])
// ------------------------------------------------------------------
__global__ __launch_bounds__(256)
void gemm_sim_k(const float* __restrict__ cmp, const float* __restrict__ src,
                const float* __restrict__ cn, const float* __restrict__ sn,
                int M, float* __restrict__ sim)
{
    const int b  = blockIdx.z;
    const int m0 = blockIdx.x * 64;
    const int tid = threadIdx.x;

    const float* A  = cmp + (size_t)b * M * Dv;
    const float* Bm = src + (size_t)b * Sv * Dv;

    __shared__ float As[16][68];
    __shared__ float Bs[16][132];

    float acc[4][8];
    #pragma unroll
    for (int i = 0; i < 4; ++i)
        #pragma unroll
        for (int j = 0; j < 8; ++j) acc[i][j] = 0.f;

    const int ka = tid & 15, mb = tid >> 4;

    for (int k0 = 0; k0 < Dv; k0 += 16) {
        int kk = k0 + ka;
        #pragma unroll
        for (int p = 0; p < 4; ++p) {
            int m = mb + p*16;
            As[ka][m] = (kk < Dv) ? A[(size_t)(m0 + m) * Dv + kk] : 0.f;
        }
        #pragma unroll
        for (int p = 0; p < 8; ++p) {
            int n = mb + p*16;
            Bs[ka][n] = (kk < Dv) ? Bm[(size_t)n * Dv + kk] : 0.f;
        }
        __syncthreads();
        const int ty = tid >> 4, tx = tid & 15;
        #pragma unroll
        for (int k = 0; k < 16; ++k) {
            float a[4], bv[8];
            *(float4*)&a[0]  = *(const float4*)&As[k][ty*4];
            *(float4*)&bv[0] = *(const float4*)&Bs[k][tx*8];
            *(float4*)&bv[4] = *(const float4*)&Bs[k][tx*8+4];
            #pragma unroll
            for (int i = 0; i < 4; ++i)
                #pragma unroll
                for (int j = 0; j < 8; ++j)
                    acc[i][j] = fmaf(a[i], bv[j], acc[i][j]);
        }
        __syncthreads();
    }

    const int ty = tid >> 4, tx = tid & 15;
    float cnv[4], snv[8];
    #pragma unroll
    for (int i = 0; i < 4; ++i) cnv[i] = cn[(size_t)b * M + m0 + ty*4 + i];
    #pragma unroll
    for (int j = 0; j < 8; ++j) snv[j] = sn[(size_t)b * Sv + tx*8 + j];
    #pragma unroll
    for (int i = 0; i < 4; ++i) {
        float* orow = sim + ((size_t)b * M + m0 + ty*4 + i) * Sv;
        #pragma unroll
        for (int j4 = 0; j4 < 8; j4 += 4) {
            float4 v;
            v.x = acc[i][j4+0] / (cnv[i] * snv[j4+0]);
            v.y = acc[i][j4+1] / (cnv[i] * snv[j4+1]);
            v.z = acc[i][j4+2] / (cnv[i] * snv[j4+2]);
            v.w = acc[i][j4+3] / (cnv[i] * snv[j4+3]);
            *(float4*)&orow[tx*8 + j4] = v;
        }
    }
}

// ------------------------------------------------------------------
// out[b][c][0:300] += sim[b][c][:] @ src_enc[b][:][0:300]
// ------------------------------------------------------------------
__global__ __launch_bounds__(256)
void gemm_ctx_k(const float* __restrict__ sim, const float* __restrict__ enc,
                int M, float* __restrict__ outp)
{
    const int b  = blockIdx.z;
    const int m0 = blockIdx.x * 64;
    const int n0 = blockIdx.y * 64;
    const int tid = threadIdx.x;

    const float* A  = sim + (size_t)b * M * Sv;
    const float* Bm = enc + (size_t)b * Sv * 300;

    __shared__ float As[16][68];
    __shared__ float Bs[16][68];

    float acc[4][4];
    #pragma unroll
    for (int i = 0; i < 4; ++i)
        #pragma unroll
        for (int j = 0; j < 4; ++j) acc[i][j] = 0.f;

    const int ka  = tid & 15, mb2 = tid >> 4;
    const int nb3 = tid & 63, kb3 = tid >> 6;

    for (int k0 = 0; k0 < Sv; k0 += 16) {
        #pragma unroll
        for (int p = 0; p < 4; ++p) {
            int m = mb2 + p*16;
            As[ka][m] = A[(size_t)(m0 + m) * Sv + k0 + ka];
        }
        #pragma unroll
        for (int p = 0; p < 4; ++p) {
            int k  = kb3 + p*4;
            int nn = n0 + nb3;
            Bs[k][nb3] = (nn < 300) ? Bm[(size_t)(k0 + k) * 300 + nn] : 0.f;
        }
        __syncthreads();
        const int ty = tid >> 4, tx = tid & 15;
        #pragma unroll
        for (int k = 0; k < 16; ++k) {
            float a[4], bv[4];
            *(float4*)&a[0]  = *(const float4*)&As[k][ty*4];
            *(float4*)&bv[0] = *(const float4*)&Bs[k][tx*4];
            #pragma unroll
            for (int i = 0; i < 4; ++i)
                #pragma unroll
                for (int j = 0; j < 4; ++j)
                    acc[i][j] = fmaf(a[i], bv[j], acc[i][j]);
        }
        __syncthreads();
    }

    const int ty = tid >> 4, tx = tid & 15;
    int n = n0 + tx*4;
    if (n < 300) {
        #pragma unroll
        for (int i = 0; i < 4; ++i) {
            int row = m0 + ty*4 + i;
            float4* op = (float4*)(outp + ((size_t)b * M + row) * 300 + n);
            float4 v = *op;
            v.x += acc[i][0]; v.y += acc[i][1]; v.z += acc[i][2]; v.w += acc[i][3];
            *op = v;
        }
    }
}

// ------------------------------------------------------------------
extern "C" void kernel_launch(void* const* d_in, const int* in_sizes, int n_in,
                              void* d_out, int out_size, void* d_ws, size_t ws_size,
                              hipStream_t stream)
{
    (void)in_sizes; (void)n_in; (void)out_size; (void)ws_size;
    const float* src_emb = (const float*)d_in[0];
    const float* col_emb = (const float*)d_in[1];
    const float* tab_emb = (const float*)d_in[2];
    const float* col_hot = (const float*)d_in[3];
    const float* tab_hot = (const float*)d_in[4];
    const float* Wx_f = (const float*)d_in[5];
    const float* Wh_f = (const float*)d_in[6];
    const float* b_f  = (const float*)d_in[7];
    const float* Wx_b = (const float*)d_in[8];
    const float* Wh_b = (const float*)d_in[9];
    const float* b_b  = (const float*)d_in[10];
    const float* W_col = (const float*)d_in[11];
    const float* b_col = (const float*)d_in[12];
    const float* W_tab = (const float*)d_in[13];
    const float* b_tab = (const float*)d_in[14];

    float* out      = (float*)d_out;
    float* out_src  = out;                       // [256][128][300]
    float* out_col  = out + 9830400;             // [256][256][300]
    float* out_tab  = out + 29491200;            // [256][64][300]
    float* out_cell = out + 34406400;            // [256][300]

    float* ws = (float*)d_ws;
    float* Gbuf    = ws;                         // 2*128*256*600 floats
    float* sim_col = ws;                         // reused AFTER lstm
    float* sim_tab = ws + 8388608;
    float* sn = ws + 39321600;
    float* cn = sn + 32768;
    float* tn = cn + 65536;

    // fp16 staging buffers live in the (currently dead) out_col region of
    // d_out; they are fully dead before init_enc_k/gemm_ctx_k overwrite it.
    _Float16* A16  = (_Float16*)(out + 9830400);     // [32768][320]
    _Float16* W16T = A16 + (size_t)32768 * 320;      // [2][640][320]

    // 0. fp16 conversions
    conv_a16_k<<<32768*80/256, 256, 0, stream>>>(src_emb, A16);
    conv_w16_k<<<dim3(640, 2), 320, 0, stream>>>(Wx_f, Wx_b, W16T);

    // 1. norms
    row_norm_k<<<32768/4, 256, 0, stream>>>(src_emb, 32768, sn);
    row_norm_k<<<65536/4, 256, 0, stream>>>(col_emb, 65536, cn);
    row_norm_k<<<16384/4, 256, 0, stream>>>(tab_emb, 16384, tn);

    // 2. input projection (MFMA)
    gemm_xw_mfma_k<<<dim3(256, 5, 2), 256, 0, stream>>>(A16, W16T, b_f, b_b, Gbuf);

    // 3. recurrence (MFMA)
    lstm_mfma_k<<<128, 640, 0, stream>>>(Gbuf, Wh_f, Wh_b, out_src, out_cell);

    // 4. out = emb + hot@W + bias  (overwrites A16/W16T region — after gemm)
    init_enc_k<<<65536/64, 256, 0, stream>>>(col_emb, col_hot, W_col, b_col, 9, out_col);
    init_enc_k<<<16384/64, 256, 0, stream>>>(tab_emb, tab_hot, W_tab, b_tab, 5, out_tab);

    // 5. cosine similarity (overwrites Gbuf region — must come after lstm)
    gemm_sim_k<<<dim3(4, 1, 256), 256, 0, stream>>>(col_emb, src_emb, cn, sn, 256, sim_col);
    gemm_sim_k<<<dim3(1, 1, 256), 256, 0, stream>>>(tab_emb, src_emb, tn, sn, 64, sim_tab);

    // 6. context accumulation
    gemm_ctx_k<<<dim3(4, 5, 256), 256, 0, stream>>>(sim_col, out_src, 256, out_col);
    gemm_ctx_k<<<dim3(1, 5, 256), 256, 0, stream>>>(sim_tab, out_src, 64, out_tab);
}

// Round 6
// 688.375 us; speedup vs baseline: 4.9883x; 1.1161x over previous
//
#include <hip/hip_runtime.h>
#include <math.h>

#define Bv 256
#define Sv 128
#define Cv 256
#define Tv 64
#define Dv 300
#define Hv 150
#define G4v 600   // 4*H

typedef _Float16 h8v __attribute__((ext_vector_type(8)));
typedef _Float16 h4v __attribute__((ext_vector_type(4)));
typedef float    f4v __attribute__((ext_vector_type(4)));

// ------------------------------------------------------------------
// row L2 norm (length 300), one wave per row: out[r] = max(||x_r||, 1e-8)
// ------------------------------------------------------------------
__global__ __launch_bounds__(256)
void row_norm_k(const float* __restrict__ x, int rows, float* __restrict__ out)
{
    int gtid = blockIdx.x * 256 + threadIdx.x;
    int wave = gtid >> 6;
    int lane = threadIdx.x & 63;
    if (wave >= rows) return;
    const float* row = x + (size_t)wave * Dv;
    float s = 0.f;
    for (int k = lane; k < Dv; k += 64) { float v = row[k]; s += v * v; }
    #pragma unroll
    for (int off = 32; off > 0; off >>= 1) s += __shfl_down(s, off, 64);
    if (lane == 0) out[wave] = fmaxf(sqrtf(s), 1e-8f);
}

// ------------------------------------------------------------------
// generic fp32 [rows][300] -> fp16 [rows][320] (k>=300 zero)
// launch rows*80/256 blocks
// ------------------------------------------------------------------
__global__ __launch_bounds__(256)
void conv_a16_k(const float* __restrict__ A, _Float16* __restrict__ A16)
{
    int idx = blockIdx.x * 256 + threadIdx.x;
    int row = idx / 80;
    int k   = (idx - row * 80) * 4;
    float4 v = {0.f, 0.f, 0.f, 0.f};
    if (k < Dv) v = *(const float4*)&A[(size_t)row * Dv + k];
    h4v o;
    o[0] = (_Float16)v.x; o[1] = (_Float16)v.y;
    o[2] = (_Float16)v.z; o[3] = (_Float16)v.w;
    *(h4v*)&A16[(size_t)row * 320 + k] = o;
}

// ------------------------------------------------------------------
// Wx fp32 [300][600] -> W16T fp16 [dir][640][320] transposed, zero-padded
// ------------------------------------------------------------------
__global__ __launch_bounds__(320)
void conv_w16_k(const float* __restrict__ Wf, const float* __restrict__ Wb,
                _Float16* __restrict__ W16T)
{
    const int n   = blockIdx.x;      // 0..639
    const int dir = blockIdx.y;      // 0..1
    const int k   = threadIdx.x;     // 0..319
    const float* W = dir ? Wb : Wf;
    float v = (k < Dv && n < G4v) ? W[(size_t)k * G4v + n] : 0.f;
    W16T[((size_t)dir * 640 + n) * 320 + k] = (_Float16)v;
}

// ------------------------------------------------------------------
// MFMA input projection: G[dir][s][b][0:600] = src @ Wx_dir + b_dir
// ------------------------------------------------------------------
__global__ __launch_bounds__(256)
void gemm_xw_mfma_k(const _Float16* __restrict__ A16,
                    const _Float16* __restrict__ W16T,
                    const float* __restrict__ bf, const float* __restrict__ bb,
                    float* __restrict__ Gout)
{
    const int m0  = blockIdx.x * 128;
    const int n0  = blockIdx.y * 128;
    const int dir = blockIdx.z;
    const float* bias = dir ? bb : bf;
    const _Float16* Wd = W16T + (size_t)dir * 640 * 320;

    __shared__ _Float16 As[128][40];
    __shared__ _Float16 Bs[128][40];

    const int tid  = threadIdx.x;
    const int lane = tid & 63;
    const int w    = tid >> 6;
    const int wm   = w >> 1, wn = w & 1;
    const int r16  = lane & 15, q = lane >> 4;

    const int srow  = tid >> 1;
    const int sslot = (tid & 1) * 16;

    f4v acc[4][4];
    #pragma unroll
    for (int i = 0; i < 4; ++i)
        #pragma unroll
        for (int j = 0; j < 4; ++j) acc[i][j] = (f4v){0.f,0.f,0.f,0.f};

    for (int k0 = 0; k0 < 320; k0 += 32) {
        h8v av0 = *(const h8v*)&A16[(size_t)(m0 + srow) * 320 + k0 + sslot];
        h8v av1 = *(const h8v*)&A16[(size_t)(m0 + srow) * 320 + k0 + sslot + 8];
        h8v bv0 = *(const h8v*)&Wd [(size_t)(n0 + srow) * 320 + k0 + sslot];
        h8v bv1 = *(const h8v*)&Wd [(size_t)(n0 + srow) * 320 + k0 + sslot + 8];
        __syncthreads();
        *(h8v*)&As[srow][sslot]     = av0;
        *(h8v*)&As[srow][sslot + 8] = av1;
        *(h8v*)&Bs[srow][sslot]     = bv0;
        *(h8v*)&Bs[srow][sslot + 8] = bv1;
        __syncthreads();

        h8v af[4], bfr[4];
        #pragma unroll
        for (int mi = 0; mi < 4; ++mi)
            af[mi] = *(const h8v*)&As[wm*64 + mi*16 + r16][q*8];
        #pragma unroll
        for (int ni = 0; ni < 4; ++ni)
            bfr[ni] = *(const h8v*)&Bs[wn*64 + ni*16 + r16][q*8];
        #pragma unroll
        for (int mi = 0; mi < 4; ++mi)
            #pragma unroll
            for (int ni = 0; ni < 4; ++ni)
                acc[mi][ni] = __builtin_amdgcn_mfma_f32_16x16x32_f16(
                                  af[mi], bfr[ni], acc[mi][ni], 0, 0, 0);
    }

    #pragma unroll
    for (int ni = 0; ni < 4; ++ni) {
        int n = n0 + wn*64 + ni*16 + r16;
        if (n >= G4v) continue;
        float bn = bias[n];
        #pragma unroll
        for (int mi = 0; mi < 4; ++mi) {
            #pragma unroll
            for (int r = 0; r < 4; ++r) {
                int row = m0 + wm*64 + mi*16 + q*4 + r;
                int b   = row >> 7;
                int s   = row & 127;
                Gout[(((size_t)dir * Sv + s) * Bv + b) * G4v + n] = acc[mi][ni][r] + bn;
            }
        }
    }
}

// ------------------------------------------------------------------
// MFMA LSTM recurrence v2: same structure as round 4 but the per-step
// barrier is lgkmcnt-only (raw s_barrier) so the G prefetch and out_src
// stores stay in flight across steps; prefetch issued at top of step.
// ------------------------------------------------------------------
__device__ __forceinline__ float sigm(float x) { return 1.0f / (1.0f + expf(-x)); }

__global__ __launch_bounds__(640, 1)
void lstm_mfma_k(const float* __restrict__ G,      // [2][S][B][600] bias incl.
                 const float* __restrict__ Wh_f, const float* __restrict__ Wh_b,
                 float* __restrict__ out_src,      // [B][S][300]
                 float* __restrict__ out_cell)     // [B][300]
{
    const int blk = blockIdx.x;          // 0..127
    const int dir = blk & 1;
    const int b0  = (blk >> 1) * 4;
    const float* Wh = dir ? Wh_b : Wh_f;
    const float* Gd = G + (size_t)dir * Sv * Bv * G4v;

    const int tid  = threadIdx.x;
    const int w    = tid >> 6;           // wave 0..9
    const int lane = tid & 63;
    const int q    = lane >> 4;          // 0..3
    const int cp   = lane & 15;          // 0..15
    const int hcol = w * 16 + cp;        // 0..159
    const bool colok = (hcol < Hv);

    __shared__ _Float16 h_sh[2][16][168];
    __shared__ float    g_sh[10][4][16][4];   // [wave][gate][col][row]

    h8v Bf[4][5];
    #pragma unroll
    for (int g = 0; g < 4; ++g) {
        #pragma unroll
        for (int ks = 0; ks < 5; ++ks) {
            h8v v;
            #pragma unroll
            for (int j = 0; j < 8; ++j) {
                int k = 32*ks + 8*q + j;
                float x = (k < Hv && colok) ? Wh[(size_t)k * G4v + hcol + ((g*Hv))] : 0.f;
                v[j] = (_Float16)x;
            }
            Bf[g][ks] = v;
        }
    }

    for (int i = tid; i < 2*16*168; i += 640)
        ((_Float16*)h_sh)[i] = (_Float16)0.f;

    float c = 0.f;
    const int rp = q;

    float gc0, gc1, gc2, gc3;
    {
        int ss0 = dir ? (Sv - 1) : 0;
        const float* p = Gd + ((size_t)ss0 * Bv + b0 + rp) * G4v;
        gc0 = colok ? p[0*Hv + hcol] : 0.f;
        gc1 = colok ? p[1*Hv + hcol] : 0.f;
        gc2 = colok ? p[2*Hv + hcol] : 0.f;
        gc3 = colok ? p[3*Hv + hcol] : 0.f;
    }
    __syncthreads();

    int cur = 0;
    for (int s = 0; s < Sv; ++s) {
        const int ss = dir ? (Sv - 1 - s) : s;

        // prefetch next step's G at TOP of step (full step of latency cover;
        // raw barrier below does NOT drain vmcnt)
        float gn0 = 0.f, gn1 = 0.f, gn2 = 0.f, gn3 = 0.f;
        if (s + 1 < Sv) {
            int ssn = dir ? (ss - 1) : (ss + 1);
            const float* p = Gd + ((size_t)ssn * Bv + b0 + rp) * G4v;
            if (colok) {
                gn0 = p[0*Hv + hcol]; gn1 = p[1*Hv + hcol];
                gn2 = p[2*Hv + hcol]; gn3 = p[3*Hv + hcol];
            }
        }

        f4v a0 = {0.f,0.f,0.f,0.f}, a1 = a0, a2 = a0, a3 = a0;
        #pragma unroll
        for (int ks = 0; ks < 5; ++ks) {
            h8v af = *(const h8v*)&h_sh[cur][cp][32*ks + 8*q];
            a0 = __builtin_amdgcn_mfma_f32_16x16x32_f16(af, Bf[0][ks], a0, 0, 0, 0);
            a1 = __builtin_amdgcn_mfma_f32_16x16x32_f16(af, Bf[1][ks], a1, 0, 0, 0);
            a2 = __builtin_amdgcn_mfma_f32_16x16x32_f16(af, Bf[2][ks], a2, 0, 0, 0);
            a3 = __builtin_amdgcn_mfma_f32_16x16x32_f16(af, Bf[3][ks], a3, 0, 0, 0);
        }

        if (q == 0) {
            *(f4v*)&g_sh[w][0][cp][0] = a0;
            *(f4v*)&g_sh[w][1][cp][0] = a1;
            *(f4v*)&g_sh[w][2][cp][0] = a2;
            *(f4v*)&g_sh[w][3][cp][0] = a3;
        }
        float gi = g_sh[w][0][cp][rp] + gc0;
        float gf = g_sh[w][1][cp][rp] + gc1;
        float gg = g_sh[w][2][cp][rp] + gc2;
        float go = g_sh[w][3][cp][rp] + gc3;

        float I  = sigm(gi);
        float F  = sigm(gf);
        float Gt = tanhf(gg);
        float O  = sigm(go);
        c = F * c + I * Gt;
        float h = O * tanhf(c);

        h_sh[cur ^ 1][rp][hcol] = (_Float16)h;
        if (colok)
            out_src[(((size_t)(b0 + rp)) * Sv + ss) * (2*Hv) + dir*Hv + hcol] = h;

        gc0 = gn0; gc1 = gn1; gc2 = gn2; gc3 = gn3;
        cur ^= 1;

        // lgkmcnt-only barrier: LDS (h_sh) visibility without vmcnt drain
        asm volatile("s_waitcnt lgkmcnt(0)" ::: "memory");
        __builtin_amdgcn_s_barrier();
        __builtin_amdgcn_sched_barrier(0);
    }

    if (colok)
        out_cell[(size_t)(b0 + rp) * (2*Hv) + dir*Hv + hcol] = c;
}

// ------------------------------------------------------------------
// transpose src_encoding: out_src fp32 [B][S][300] -> hi/lo fp16 [B][320][128]
// (split precision: x = hi + lo at ~fp32 accuracy). grid (2, 5, 256).
// ------------------------------------------------------------------
__global__ __launch_bounds__(256)
void trans_enc_k(const float* __restrict__ enc,
                 _Float16* __restrict__ hi, _Float16* __restrict__ lo)
{
    const int b  = blockIdx.z;
    const int s0 = blockIdx.x * 64;
    const int n0 = blockIdx.y * 64;
    __shared__ float t[64][65];
    const int tid = threadIdx.x;
    const int j  = tid & 63;
    const int i0 = (tid >> 6) * 16;
    #pragma unroll
    for (int ii = 0; ii < 16; ++ii) {
        int i = i0 + ii;
        int n = n0 + j;
        t[i][j] = (n < Dv) ? enc[((size_t)b*Sv + s0 + i)*Dv + n] : 0.f;
    }
    __syncthreads();
    #pragma unroll
    for (int ii = 0; ii < 16; ++ii) {
        int nr = i0 + ii;
        float v = t[j][nr];
        _Float16 hh = (_Float16)v;
        float l = v - (float)hh;
        size_t o = ((size_t)b*320 + n0 + nr)*128 + s0 + j;
        hi[o] = hh;
        lo[o] = (_Float16)l;
    }
}

// ------------------------------------------------------------------
// MFMA cosine-sim: sim16[b][m][s] = (cmp16[b,m,:].src16[b,s,:])/(cn*sn)
// tile 128x128xK320, structure cloned from gemm_xw_mfma_k.
// ------------------------------------------------------------------
__global__ __launch_bounds__(256)
void gemm_sim_mfma_k(const _Float16* __restrict__ cmp16,  // [Bz][M][320]
                     const _Float16* __restrict__ src16,  // [B*128][320]
                     const float* __restrict__ cn, const float* __restrict__ sn,
                     int M, _Float16* __restrict__ sim16) // [Bz][M][128]
{
    const int m0 = blockIdx.x * 128;
    const int b  = blockIdx.z;
    const _Float16* A  = cmp16 + (size_t)b * M * 320;
    const _Float16* Bm = src16 + (size_t)b * 128 * 320;

    __shared__ _Float16 As[128][40];
    __shared__ _Float16 Bs[128][40];

    const int tid  = threadIdx.x;
    const int lane = tid & 63;
    const int w    = tid >> 6;
    const int wm   = w >> 1, wn = w & 1;
    const int r16  = lane & 15, q = lane >> 4;

    const int srow  = tid >> 1;
    const int sslot = (tid & 1) * 16;
    const int arow  = (m0 + srow < M) ? (m0 + srow) : 0;   // clamp (tab M=64)

    f4v acc[4][4];
    #pragma unroll
    for (int i = 0; i < 4; ++i)
        #pragma unroll
        for (int j = 0; j < 4; ++j) acc[i][j] = (f4v){0.f,0.f,0.f,0.f};

    for (int k0 = 0; k0 < 320; k0 += 32) {
        h8v av0 = *(const h8v*)&A [(size_t)arow * 320 + k0 + sslot];
        h8v av1 = *(const h8v*)&A [(size_t)arow * 320 + k0 + sslot + 8];
        h8v bv0 = *(const h8v*)&Bm[(size_t)srow * 320 + k0 + sslot];
        h8v bv1 = *(const h8v*)&Bm[(size_t)srow * 320 + k0 + sslot + 8];
        __syncthreads();
        *(h8v*)&As[srow][sslot]     = av0;
        *(h8v*)&As[srow][sslot + 8] = av1;
        *(h8v*)&Bs[srow][sslot]     = bv0;
        *(h8v*)&Bs[srow][sslot + 8] = bv1;
        __syncthreads();

        h8v af[4], bfr[4];
        #pragma unroll
        for (int mi = 0; mi < 4; ++mi)
            af[mi] = *(const h8v*)&As[wm*64 + mi*16 + r16][q*8];
        #pragma unroll
        for (int ni = 0; ni < 4; ++ni)
            bfr[ni] = *(const h8v*)&Bs[wn*64 + ni*16 + r16][q*8];
        #pragma unroll
        for (int mi = 0; mi < 4; ++mi)
            #pragma unroll
            for (int ni = 0; ni < 4; ++ni)
                acc[mi][ni] = __builtin_amdgcn_mfma_f32_16x16x32_f16(
                                  af[mi], bfr[ni], acc[mi][ni], 0, 0, 0);
    }

    #pragma unroll
    for (int ni = 0; ni < 4; ++ni) {
        int s = wn*64 + ni*16 + r16;          // col dim = s (128)
        float snv = sn[(size_t)b * 128 + s];
        #pragma unroll
        for (int mi = 0; mi < 4; ++mi) {
            #pragma unroll
            for (int r = 0; r < 4; ++r) {
                int m = m0 + wm*64 + mi*16 + q*4 + r;
                if (m < M) {
                    float v = acc[mi][ni][r] / (cn[(size_t)b * M + m] * snv);
                    sim16[((size_t)b * M + m) * 128 + s] = (_Float16)v;
                }
            }
        }
    }
}

// ------------------------------------------------------------------
// Fused context + type-encoder epilogue:
// out[b][m][n] = emb + bias[n] + hot@W + sum_s sim16[b][m][s]*enc[b][s][n]
// enc given as split fp16 (hi+lo) transposed [B][320][128]; K=128 single
// stage; B-frags are contiguous h8v global loads. grid (M/64, 1, 256).
// ------------------------------------------------------------------
__global__ __launch_bounds__(256, 2)
void gemm_ctx_fused_k(const _Float16* __restrict__ sim16,  // [Bz][M][128]
                      const _Float16* __restrict__ encHi,
                      const _Float16* __restrict__ encLo,  // [B][320][128]
                      const float* __restrict__ emb,       // [Bz][M][300]
                      const float* __restrict__ hot,       // [Bz][M][hd]
                      const float* __restrict__ W,         // [hd][300]
                      const float* __restrict__ bias,      // [300]
                      int M, int hd, float* __restrict__ outp)
{
    const int b  = blockIdx.z;
    const int m0 = blockIdx.x * 64;
    const int tid = threadIdx.x;
    const int lane = tid & 63;
    const int w = tid >> 6;              // wave 0..3 -> n base w*80
    const int q = lane >> 4, cp = lane & 15;

    __shared__ _Float16 As[64][136];
    __shared__ float Wsh[9*304];
    __shared__ float bsh[304];
    __shared__ float hotsh[64*9];

    // stage sim16 tile [64][128]
    {
        const int srow = tid >> 2;
        const int scol = (tid & 3) * 32;
        const _Float16* src = sim16 + ((size_t)b * M + m0 + srow) * 128 + scol;
        *(h8v*)&As[srow][scol]      = *(const h8v*)&src[0];
        *(h8v*)&As[srow][scol + 8]  = *(const h8v*)&src[8];
        *(h8v*)&As[srow][scol + 16] = *(const h8v*)&src[16];
        *(h8v*)&As[srow][scol + 24] = *(const h8v*)&src[24];
    }
    for (int i = tid; i < hd*304; i += 256) {
        int jj = i / 304, nn = i - jj*304;
        Wsh[i] = (nn < Dv) ? W[(size_t)jj * Dv + nn] : 0.f;
    }
    for (int i = tid; i < 304; i += 256) bsh[i] = (i < Dv) ? bias[i] : 0.f;
    for (int i = tid; i < 64*hd; i += 256) hotsh[i] = hot[((size_t)b * M + m0) * hd + i];
    __syncthreads();

    // A-frags (K=128 -> 4 ks)
    h8v af[4][4];
    #pragma unroll
    for (int mi = 0; mi < 4; ++mi)
        #pragma unroll
        for (int ks = 0; ks < 4; ++ks)
            af[mi][ks] = *(const h8v*)&As[mi*16 + cp][32*ks + 8*q];

    f4v acc[4][5];
    #pragma unroll
    for (int mi = 0; mi < 4; ++mi)
        #pragma unroll
        for (int nt = 0; nt < 5; ++nt) acc[mi][nt] = (f4v){0.f,0.f,0.f,0.f};

    const int nbase = w * 80;
    // pass 1: hi plane, pass 2: lo plane (split-fp16 ~ fp32 B accuracy)
    #pragma unroll
    for (int pass = 0; pass < 2; ++pass) {
        const _Float16* encp = pass ? encLo : encHi;
        #pragma unroll
        for (int nt = 0; nt < 5; ++nt) {
            int n = nbase + nt*16 + cp;
            const _Float16* bp = encp + ((size_t)b * 320 + n) * 128 + 8*q;
            h8v b0 = *(const h8v*)&bp[0];
            h8v b1 = *(const h8v*)&bp[32];
            h8v b2 = *(const h8v*)&bp[64];
            h8v b3 = *(const h8v*)&bp[96];
            #pragma unroll
            for (int mi = 0; mi < 4; ++mi) {
                acc[mi][nt] = __builtin_amdgcn_mfma_f32_16x16x32_f16(af[mi][0], b0, acc[mi][nt], 0, 0, 0);
                acc[mi][nt] = __builtin_amdgcn_mfma_f32_16x16x32_f16(af[mi][1], b1, acc[mi][nt], 0, 0, 0);
                acc[mi][nt] = __builtin_amdgcn_mfma_f32_16x16x32_f16(af[mi][2], b2, acc[mi][nt], 0, 0, 0);
                acc[mi][nt] = __builtin_amdgcn_mfma_f32_16x16x32_f16(af[mi][3], b3, acc[mi][nt], 0, 0, 0);
            }
        }
    }

    // epilogue: + emb + bias + hot@W, write out
    #pragma unroll
    for (int nt = 0; nt < 5; ++nt) {
        int n = nbase + nt*16 + cp;
        if (n >= Dv) continue;
        float bn = bsh[n];
        #pragma unroll
        for (int mi = 0; mi < 4; ++mi) {
            #pragma unroll
            for (int r = 0; r < 4; ++r) {
                int ml = mi*16 + 4*q + r;          // local row
                int m  = m0 + ml;
                float v = acc[mi][nt][r] + bn + emb[((size_t)b * M + m) * Dv + n];
                for (int jj = 0; jj < hd; ++jj)
                    v = fmaf(hotsh[ml*hd + jj], Wsh[jj*304 + n], v);
                outp[((size_t)b * M + m) * Dv + n] = v;
            }
        }
    }
}

// ------------------------------------------------------------------
extern "C" void kernel_launch(void* const* d_in, const int* in_sizes, int n_in,
                              void* d_out, int out_size, void* d_ws, size_t ws_size,
                              hipStream_t stream)
{
    (void)in_sizes; (void)n_in; (void)out_size; (void)ws_size;
    const float* src_emb = (const float*)d_in[0];
    const float* col_emb = (const float*)d_in[1];
    const float* tab_emb = (const float*)d_in[2];
    const float* col_hot = (const float*)d_in[3];
    const float* tab_hot = (const float*)d_in[4];
    const float* Wx_f = (const float*)d_in[5];
    const float* Wh_f = (const float*)d_in[6];
    const float* b_f  = (const float*)d_in[7];
    const float* Wx_b = (const float*)d_in[8];
    const float* Wh_b = (const float*)d_in[9];
    const float* b_b  = (const float*)d_in[10];
    const float* W_col = (const float*)d_in[11];
    const float* b_col = (const float*)d_in[12];
    const float* W_tab = (const float*)d_in[13];
    const float* b_tab = (const float*)d_in[14];

    float* out      = (float*)d_out;
    float* out_src  = out;                       // [256][128][300]
    float* out_col  = out + 9830400;             // [256][256][300]
    float* out_tab  = out + 29491200;            // [256][64][300]
    float* out_cell = out + 34406400;            // [256][300]

    float* ws = (float*)d_ws;
    float* Gbuf = ws;                            // 2*128*256*600 floats (157MB)
    // after lstm, Gbuf region is reused:
    _Float16* encHi    = (_Float16*)(ws);             // 256*320*128 = 10.49M halves
    _Float16* encLo    = (_Float16*)(ws + 5242880);   // same size
    _Float16* sim16_col= (_Float16*)(ws + 11000000);  // 256*256*128 halves
    _Float16* sim16_tab= (_Float16*)(ws + 16000000);  // 256*64*128 halves
    float* sn = ws + 39321600;                   // [B*S]  32768
    float* cn = sn + 32768;                      // [B*C]  65536
    float* tn = cn + 65536;                      // [B*T]  16384

    // fp16 staging in currently-dead d_out regions (dead before overwrite):
    _Float16* A16   = (_Float16*)(out + 9830400);          // [32768][320]
    _Float16* W16T  = A16 + (size_t)32768 * 320;           // [2][640][320]
    _Float16* col16 = (_Float16*)(out + 15278080);         // [65536][320]
    _Float16* tab16 = (_Float16*)(out + 29491200);         // [16384][320]

    // 0. fp16 conversions
    conv_a16_k<<<32768*80/256, 256, 0, stream>>>(src_emb, A16);
    conv_a16_k<<<65536*80/256, 256, 0, stream>>>(col_emb, col16);
    conv_a16_k<<<16384*80/256, 256, 0, stream>>>(tab_emb, tab16);
    conv_w16_k<<<dim3(640, 2), 320, 0, stream>>>(Wx_f, Wx_b, W16T);

    // 1. norms
    row_norm_k<<<32768/4, 256, 0, stream>>>(src_emb, 32768, sn);
    row_norm_k<<<65536/4, 256, 0, stream>>>(col_emb, 65536, cn);
    row_norm_k<<<16384/4, 256, 0, stream>>>(tab_emb, 16384, tn);

    // 2. input projection (MFMA)
    gemm_xw_mfma_k<<<dim3(256, 5, 2), 256, 0, stream>>>(A16, W16T, b_f, b_b, Gbuf);

    // 3. recurrence (MFMA, raw-barrier)
    lstm_mfma_k<<<128, 640, 0, stream>>>(Gbuf, Wh_f, Wh_b, out_src, out_cell);

    // 4. transpose + split src_encoding -> [B][320][128] hi/lo (Gbuf now dead)
    trans_enc_k<<<dim3(2, 5, 256), 256, 0, stream>>>(out_src, encHi, encLo);

    // 5. cosine similarity (MFMA) -> fp16 sim
    gemm_sim_mfma_k<<<dim3(2, 1, 256), 256, 0, stream>>>(col16, A16, cn, sn, 256, sim16_col);
    gemm_sim_mfma_k<<<dim3(1, 1, 256), 256, 0, stream>>>(tab16, A16, tn, sn, 64,  sim16_tab);

    // 6. fused context + type encoder (overwrites staging regions, now dead)
    gemm_ctx_fused_k<<<dim3(4, 1, 256), 256, 0, stream>>>(
        sim16_col, encHi, encLo, col_emb, col_hot, W_col, b_col, 256, 9, out_col);
    gemm_ctx_fused_k<<<dim3(1, 1, 256), 256, 0, stream>>>(
        sim16_tab, encHi, encLo, tab_emb, tab_hot, W_tab, b_tab, 64, 5, out_tab);
}